// Round 5
// baseline (261.996 us; speedup 1.0000x reference)
//
#include <hip/hip_runtime.h>
#include <hip/hip_bf16.h>

#define T_SEQ 1024
#define U_DIM 512
#define LN_EPS 1e-3f
#define LOG2E 1.44269504f

typedef float  f32x4  __attribute__((ext_vector_type(4)));
typedef short  bf16x8 __attribute__((ext_vector_type(8)));

__device__ __forceinline__ unsigned short f2bf(float f) {
    union { float f; unsigned u; } x; x.f = f;
    unsigned r = x.u + 0x7fffu + ((x.u >> 16) & 1u);   // RNE
    return (unsigned short)(r >> 16);
}
__device__ __forceinline__ float b2f(short s) {
    union { unsigned u; float f; } x; x.u = ((unsigned)(unsigned short)s) << 16;
    return x.f;
}
__device__ __forceinline__ int packbf(float a, float b) {
    return (int)((unsigned)f2bf(a) | ((unsigned)f2bf(b) << 16));
}
__device__ __forceinline__ void async_copy16(void* lds, const void* g) {
    __builtin_amdgcn_global_load_lds((const __attribute__((address_space(1))) void*)g,
                                     (__attribute__((address_space(3))) void*)lds, 16, 0, 0);
}

#define WAITV(N) asm volatile("s_waitcnt vmcnt(" #N ")" ::: "memory")

// ---------------------------------------------------------------------------
// prep_all: blocks 0..255 transpose W -> Wt bf16; blocks 256..2303 convert
// q,k,v fp32 -> bf16 (RNE). One dispatch.
// ---------------------------------------------------------------------------
__global__ __launch_bounds__(256) void prep_all(
        const float* __restrict__ Wq, const float* __restrict__ Wk,
        const float* __restrict__ Wv, const float* __restrict__ Wo,
        short* __restrict__ wt,
        const float* __restrict__ q, const float* __restrict__ k, const float* __restrict__ v,
        short* __restrict__ qb, short* __restrict__ kb, short* __restrict__ vb) {
    __shared__ float Ws[64][65];
    const int bid = blockIdx.x, t = threadIdx.x;
    if (bid >= 256) {
        const size_t off = ((size_t)(bid - 256) * 256 + t) * 8;
#pragma unroll
        for (int z = 0; z < 3; ++z) {
            const float* src = (z == 0) ? q : (z == 1) ? k : v;
            short* dst = (z == 0) ? qb : (z == 1) ? kb : vb;
            float4 a = *(const float4*)(src + off);
            float4 b = *(const float4*)(src + off + 4);
            int4 o;
            o.x = packbf(a.x, a.y);
            o.y = packbf(a.z, a.w);
            o.z = packbf(b.x, b.y);
            o.w = packbf(b.z, b.w);
            *(int4*)(dst + off) = o;
        }
        return;
    }
    const int z = bid >> 6, tile = bid & 63;
    const float* W = (z == 0) ? Wq : (z == 1) ? Wk : (z == 2) ? Wv : Wo;
    short* Wt = wt + (size_t)z * 262144;
    const int k0 = (tile >> 3) * 64, n0 = (tile & 7) * 64;
    {
        const int kr = t >> 2, cs = (t & 3) * 16;
        const float4* src = (const float4*)(W + (size_t)(k0 + kr) * 512 + n0 + cs);
#pragma unroll
        for (int i = 0; i < 4; ++i) {
            float4 vv = src[i];
            Ws[kr][cs + 4 * i + 0] = vv.x;
            Ws[kr][cs + 4 * i + 1] = vv.y;
            Ws[kr][cs + 4 * i + 2] = vv.z;
            Ws[kr][cs + 4 * i + 3] = vv.w;
        }
    }
    __syncthreads();
    {
        const int nr = t >> 2, ks = (t & 3) * 16;
        int4 w0, w1;
        w0.x = packbf(Ws[ks + 0][nr], Ws[ks + 1][nr]);
        w0.y = packbf(Ws[ks + 2][nr], Ws[ks + 3][nr]);
        w0.z = packbf(Ws[ks + 4][nr], Ws[ks + 5][nr]);
        w0.w = packbf(Ws[ks + 6][nr], Ws[ks + 7][nr]);
        w1.x = packbf(Ws[ks + 8][nr], Ws[ks + 9][nr]);
        w1.y = packbf(Ws[ks + 10][nr], Ws[ks + 11][nr]);
        w1.z = packbf(Ws[ks + 12][nr], Ws[ks + 13][nr]);
        w1.w = packbf(Ws[ks + 14][nr], Ws[ks + 15][nr]);
        short* dst = Wt + (size_t)(n0 + nr) * 512 + k0 + ks;
        *(int4*)dst = w0;
        *(int4*)(dst + 8) = w1;
    }
}

// ---------------------------------------------------------------------------
// MFMA GEMM, counted-vmcnt 4-deep pipeline. BK=32, 4 LDS buffers, prefetch
// depth 3, steady-state s_waitcnt vmcnt(2*LPW) (never 0 until tail).
// OUT=0: bf16 out. OUT=1: fp32 out + residual after relu.
// ---------------------------------------------------------------------------
template <int OUT, int BM, int BN>
__global__ __launch_bounds__(256) void gemm_mfma(
        const void* __restrict__ A0, const void* __restrict__ A1, const void* __restrict__ A2,
        const short* __restrict__ Wt0, const short* __restrict__ Wt1, const short* __restrict__ Wt2,
        const float* __restrict__ b0p, const float* __restrict__ b1p, const float* __restrict__ b2p,
        const float* __restrict__ resid,
        void* __restrict__ O0, void* __restrict__ O1, void* __restrict__ O2) {
    constexpr int ASZ = BM * 32;          // shorts per A tile
    constexpr int BSZ = BN * 32;          // shorts per B tile
    constexpr int TSZ = ASZ + BSZ;
    constexpr int NA  = BM / 16;          // A cells (16 rows x 32 k each)
    constexpr int NB  = BN / 16;          // B cells
    constexpr int MW  = BM / 64;          // waves along m
    constexpr int NW  = 4 / MW;           // waves along n
    constexpr int AJ  = BN / (16 * NW);   // n-frags per wave
    constexpr int LPW = (NA + NB) / 4;    // loads per wave per tile
    static_assert((NA + NB) % 4 == 0, "cells divisible by waves");
    __shared__ short Ls[4 * TSZ];

    const int z = blockIdx.z;
    const void* Av = (z == 0) ? A0 : (z == 1) ? A1 : A2;
    const short* Wz = (z == 0) ? Wt0 : (z == 1) ? Wt1 : Wt2;
    const float* bz = (z == 0) ? b0p : (z == 1) ? b1p : b2p;
    void* Ov = (z == 0) ? O0 : (z == 1) ? O1 : O2;

    const int tid = threadIdx.x;
    const int m0 = blockIdx.x * BM, n0 = blockIdx.y * BN;
    const int w = tid >> 6, lane = tid & 63;
    const int n15 = lane & 15, g = lane >> 4;
    const int mh = w / NW, nh = w % NW;

    f32x4 acc[4][AJ];
#pragma unroll
    for (int i = 0; i < 4; ++i)
#pragma unroll
        for (int j = 0; j < AJ; ++j) acc[i][j] = (f32x4){0.f, 0.f, 0.f, 0.f};

    // per-wave staging descriptors
    const short* gsrc[LPW];
    int loff[LPW];
#pragma unroll
    for (int cl = 0; cl < LPW; ++cl) {
        const int cid = w * LPW + cl;
        if (cid < NA) {
            gsrc[cl] = (const short*)Av + (size_t)(m0 + cid * 16 + n15) * 512 + g * 8;
            loff[cl] = cid * 512;
        } else {
            const int c2 = cid - NA;
            gsrc[cl] = Wz + (size_t)(n0 + c2 * 16 + n15) * 512 + g * 8;
            loff[cl] = ASZ + c2 * 512;
        }
    }

#define STAGE(CK, BUF)                                                                   \
    do {                                                                                 \
        _Pragma("unroll")                                                                \
        for (int cl = 0; cl < LPW; ++cl)                                                 \
            async_copy16(Ls + (BUF) * TSZ + loff[cl], gsrc[cl] + (CK) * 32);             \
    } while (0)

    STAGE(0, 0);
    STAGE(1, 1);
    STAGE(2, 2);

    for (int ck = 0; ck < 16; ++ck) {
        if (ck < 14) {
            if constexpr (LPW == 3) WAITV(6); else WAITV(4);
        } else if (ck == 14) {
            if constexpr (LPW == 3) WAITV(3); else WAITV(2);
        } else {
            WAITV(0);
        }
        __builtin_amdgcn_s_barrier();
        __builtin_amdgcn_sched_barrier(0);
        if (ck + 3 <= 15) STAGE(ck + 3, (ck + 3) & 3);
        const int cb = ck & 3;
        bf16x8 af[4], bfv[AJ];
#pragma unroll
        for (int i = 0; i < 4; ++i)
            af[i] = *(const bf16x8*)(Ls + cb * TSZ + (mh * 4 + i) * 512 + lane * 8);
#pragma unroll
        for (int j = 0; j < AJ; ++j)
            bfv[j] = *(const bf16x8*)(Ls + cb * TSZ + ASZ + (nh * AJ + j) * 512 + lane * 8);
#pragma unroll
        for (int i = 0; i < 4; ++i)
#pragma unroll
            for (int j = 0; j < AJ; ++j)
                acc[i][j] = __builtin_amdgcn_mfma_f32_16x16x32_bf16(af[i], bfv[j], acc[i][j], 0, 0, 0);
    }
#undef STAGE

    // Epilogue
    const int mbase = m0 + mh * 64 + g * 4;
    const int nbase = n0 + nh * (AJ * 16) + n15;
    const bool even = (n15 & 1) == 0;
    float bj[AJ];
#pragma unroll
    for (int j = 0; j < AJ; ++j) bj[j] = bz[nbase + j * 16];

#pragma unroll
    for (int i = 0; i < 4; ++i) {
        const int mrow = mbase + i * 16;
#pragma unroll
        for (int j = 0; j < AJ; ++j) {
            const int ncol = nbase + j * 16;
            f32x4 a = acc[i][j];
            float v0 = fmaxf(a[0] + bj[j], 0.f);
            float v1 = fmaxf(a[1] + bj[j], 0.f);
            float v2 = fmaxf(a[2] + bj[j], 0.f);
            float v3 = fmaxf(a[3] + bj[j], 0.f);
            if (OUT == 0) {
                unsigned t01 = (unsigned)packbf(v0, v1);
                unsigned t23 = (unsigned)packbf(v2, v3);
                unsigned x01 = (unsigned)__shfl_xor((int)t01, 1, 64);
                unsigned x23 = (unsigned)__shfl_xor((int)t23, 1, 64);
                short* Oz = (short*)Ov;
                if (even) {
                    unsigned d0 = (t01 & 0xffffu) | (x01 << 16);
                    unsigned d1 = (t01 >> 16) | (x01 & 0xffff0000u);
                    *(unsigned*)(Oz + (size_t)(mrow + 0) * 512 + ncol) = d0;
                    *(unsigned*)(Oz + (size_t)(mrow + 1) * 512 + ncol) = d1;
                } else {
                    unsigned d2 = (x23 & 0xffffu) | (t23 << 16);
                    unsigned d3 = (x23 >> 16) | (t23 & 0xffff0000u);
                    *(unsigned*)(Oz + (size_t)(mrow + 2) * 512 + ncol - 1) = d2;
                    *(unsigned*)(Oz + (size_t)(mrow + 3) * 512 + ncol - 1) = d3;
                }
            } else {
                float x0 = __shfl_xor(v0, 1, 64);
                float x1 = __shfl_xor(v1, 1, 64);
                float x2 = __shfl_xor(v2, 1, 64);
                float x3 = __shfl_xor(v3, 1, 64);
                float* Oz = (float*)Ov;
                if (even) {
                    float2 r0 = *(const float2*)(resid + (size_t)(mrow + 0) * 512 + ncol);
                    float2 r1 = *(const float2*)(resid + (size_t)(mrow + 1) * 512 + ncol);
                    *(float2*)(Oz + (size_t)(mrow + 0) * 512 + ncol) = make_float2(v0 + r0.x, x0 + r0.y);
                    *(float2*)(Oz + (size_t)(mrow + 1) * 512 + ncol) = make_float2(v1 + r1.x, x1 + r1.y);
                } else {
                    float2 r2 = *(const float2*)(resid + (size_t)(mrow + 2) * 512 + ncol - 1);
                    float2 r3 = *(const float2*)(resid + (size_t)(mrow + 3) * 512 + ncol - 1);
                    *(float2*)(Oz + (size_t)(mrow + 2) * 512 + ncol - 1) = make_float2(x2 + r2.x, v2 + r2.y);
                    *(float2*)(Oz + (size_t)(mrow + 3) * 512 + ncol - 1) = make_float2(x3 + r3.x, v3 + r3.y);
                }
            }
        }
    }
}

// ---------------------------------------------------------------------------
// MFMA flash attention, SPLIT-S: each (hb, q-tile) handled by 2 blocks over
// disjoint s-ranges (flash partials: normalized O + (m,l)). 2048 blocks,
// max 8 steps/block. Map (cu&3, chunk)->(tile, half) gives every CU exactly
// 34 step-units. Partials merged by attn_combine.
// ---------------------------------------------------------------------------
__global__ __launch_bounds__(256) void attn_mfma(
        const short* __restrict__ qe, const short* __restrict__ ke,
        const short* __restrict__ ve, const float* __restrict__ pe_k,
        float* __restrict__ ml1, float* __restrict__ ml2,
        short* __restrict__ ao, short* __restrict__ ao2) {
    __shared__ short Kc[2 * 4096];    // 8 cells x 512 shorts per buf: (kh*4+mt)
    __shared__ short Vc[2 * 4096];    // 8 cells: (kh*4+dt)
    __shared__ float qpeS[4 * 16 * 17];

    const int tid = threadIdx.x;
    const int bid = blockIdx.x;
    const int cu = bid & 255, chunk = bid >> 8;
    const int hb = cu >> 2, r4 = cu & 3;
    int tt, half;
    if (chunk < 4) { tt = 4 * r4 + chunk;              half = 0; }
    else           { tt = 15 - 4 * r4 - (chunk - 4);   half = 1; }
    const int n0h = (tt + 2) >> 1;
    const int g0 = half ? n0h : 0;
    const int g1 = half ? (tt + 1) : n0h;

    const int h = hb >> 3, b = hb & 7;
    const int w = tid >> 6, lane = tid & 63;
    const int g = lane >> 4, n15 = lane & 15;
    const int sp = tid & 31, dbase = (tid >> 5) * 8;
    float* qpeW = qpeS + w * (16 * 17);

    const size_t rowbase = (size_t)b * T_SEQ;
    short* aoP = half ? ao2 : ao;
    float* mlP = half ? ml2 : ml1;

    int qn = tt * 64 + w * 16;

    // empty half (tile 0, half 1): mark l=0 and exit
    if (g0 >= g1) {
        if (g == 0)
            *(float2*)(mlP + ((size_t)hb * T_SEQ + qn + n15) * 2) = make_float2(-3.0e38f, 0.f);
        return;
    }

    bf16x8 Bq[2];
    float qpe0 = 0.f;
    float m_r = -1.0e38f, l_r = 0.f, m2 = -1.4427e38f;
    f32x4 oacc[4];

    // ---- setup: load Q frags (scaled by 1/8 exactly), qpe table, state ----
    {
#pragma unroll
        for (int kh = 0; kh < 2; ++kh) {
            bf16x8 t = *(const bf16x8*)(qe + (rowbase + qn + n15) * U_DIM + h * 64 + kh * 32 + g * 8);
#pragma unroll
            for (int i2 = 0; i2 < 8; ++i2) {
                unsigned short u = (unsigned short)t[i2];
                t[i2] = (short)(((u & 0x7f80u) > 0x0180u) ? (unsigned short)(u - 0x0180u)
                                                          : (unsigned short)(u & 0x8000u));
            }
            Bq[kh] = t;
        }
        f32x4 qa[2];
        qa[0] = (f32x4){0.f, 0.f, 0.f, 0.f};
        qa[1] = (f32x4){0.f, 0.f, 0.f, 0.f};
#pragma unroll
        for (int mt = 0; mt < 2; ++mt)
#pragma unroll
        for (int kh = 0; kh < 2; ++kh) {
            const float* src = pe_k + (mt * 16 + n15) * 64 + kh * 32 + g * 8;
            float4 f0 = *(const float4*)src;
            float4 f1 = *(const float4*)(src + 4);
            bf16x8 fr;
            fr[0] = (short)f2bf(f0.x); fr[1] = (short)f2bf(f0.y);
            fr[2] = (short)f2bf(f0.z); fr[3] = (short)f2bf(f0.w);
            fr[4] = (short)f2bf(f1.x); fr[5] = (short)f2bf(f1.y);
            fr[6] = (short)f2bf(f1.z); fr[7] = (short)f2bf(f1.w);
            qa[mt] = __builtin_amdgcn_mfma_f32_16x16x32_bf16(fr, Bq[kh], qa[mt], 0, 0, 0);
        }
#pragma unroll
        for (int mt = 0; mt < 2; ++mt)
#pragma unroll
        for (int r = 0; r < 4; ++r) {
            const int ri = mt * 16 + 4 * g + r;
            if (ri <= 16) qpeW[n15 * 17 + ri] = qa[mt][r];
        }
        qpe0 = qpeW[n15 * 17];
#pragma unroll
        for (int dt = 0; dt < 4; ++dt) oacc[dt] = (f32x4){0.f, 0.f, 0.f, 0.f};
    }

#define STAGE_K(S, BUF)                                                                  \
    do {                                                                                 \
        _Pragma("unroll")                                                                \
        for (int j = 0; j < 2; ++j) {                                                    \
            const int cc = w * 2 + j, kh = cc >> 2, mt = cc & 3;                         \
            const short* gp = ke + (rowbase + (S) + mt * 16 + n15) * U_DIM + h * 64 + kh * 32 + g * 8; \
            async_copy16(Kc + (BUF) * 4096 + cc * 512, gp);                              \
        }                                                                                \
    } while (0)

#define LOAD_V(S)                                                                        \
    do {                                                                                 \
        const short* r0 = ve + (rowbase + (S) + 2 * sp) * U_DIM + h * 64 + dbase;        \
        vx = *(const bf16x8*)r0;                                                         \
        vy = *(const bf16x8*)(r0 + U_DIM);                                               \
    } while (0)

#define STORE_V(BUF)                                                                     \
    do {                                                                                 \
        const int vkh = sp >> 4, vg = (sp & 15) >> 2, vj = (sp & 3) * 2;                 \
        _Pragma("unroll")                                                                \
        for (int i = 0; i < 8; ++i) {                                                    \
            const int d = dbase + i;                                                     \
            int pv = (int)((unsigned short)vx[i]) | (((int)(unsigned short)vy[i]) << 16);\
            *(int*)(Vc + (BUF) * 4096 + (vkh * 4 + (d >> 4)) * 512 + ((d & 15) + 16 * vg) * 8 + vj) = pv; \
        }                                                                                \
    } while (0)

    bf16x8 vx, vy;
    STAGE_K(g0 * 64, g0 & 1);
    LOAD_V(g0 * 64);
    STORE_V(g0 & 1);

    for (int gs = g0; gs < g1; ++gs) {
        const int cb = gs & 1, nb = cb ^ 1;
        const int s0 = gs * 64;
        __syncthreads();
        if (gs + 1 < g1) {
            STAGE_K((gs + 1) * 64, nb);
            LOAD_V((gs + 1) * 64);
        }

        // ---- compute step at s0 ----
        {
            int cls[4];
#pragma unroll
            for (int mt = 0; mt < 4; ++mt) {
                const int slo = s0 + mt * 16;
                cls[mt] = (slo > qn + 15) ? 0 : ((slo + 31 < qn) ? 1 : 2);
            }
            f32x4 c[4];
#pragma unroll
            for (int mt = 0; mt < 4; ++mt) c[mt] = (f32x4){0.f, 0.f, 0.f, 0.f};
            __builtin_amdgcn_s_setprio(1);
#pragma unroll
            for (int mt = 0; mt < 4; ++mt) {
                if (!cls[mt]) continue;
#pragma unroll
                for (int kh = 0; kh < 2; ++kh) {
                    bf16x8 ak = *(const bf16x8*)(Kc + cb * 4096 + (kh * 4 + mt) * 512 + lane * 8);
                    c[mt] = __builtin_amdgcn_mfma_f32_16x16x32_bf16(ak, Bq[kh], c[mt], 0, 0, 0);
                }
            }
            __builtin_amdgcn_s_setprio(0);

            const int qg = qn + n15;
            float sc[4][4];
            float pmax = -3.0e38f;
#pragma unroll
            for (int mt = 0; mt < 4; ++mt) {
                if (cls[mt] == 0) {
#pragma unroll
                    for (int r = 0; r < 4; ++r) sc[mt][r] = -3.0e38f;
                } else if (cls[mt] == 1) {
#pragma unroll
                    for (int r = 0; r < 4; ++r) {
                        sc[mt][r] = c[mt][r] + qpe0;
                        pmax = fmaxf(pmax, sc[mt][r]);
                    }
                } else {
#pragma unroll
                    for (int r = 0; r < 4; ++r) {
                        const int sg = s0 + mt * 16 + 4 * g + r;
                        const int dlt = sg - qg;
                        if (dlt <= 0) {
                            const int ri = (dlt < -16) ? 0 : (dlt + 16);
                            sc[mt][r] = c[mt][r] + qpeW[n15 * 17 + ri];
                            pmax = fmaxf(pmax, sc[mt][r]);
                        } else {
                            sc[mt][r] = -3.0e38f;
                        }
                    }
                }
            }
            pmax = fmaxf(pmax, __shfl_xor(pmax, 16, 64));
            pmax = fmaxf(pmax, __shfl_xor(pmax, 32, 64));

            // defer-max: only rescale when some row's max grew past THR=8
            const bool resc = __any(pmax > m_r + 8.0f);
            float alpha = 1.0f;
            if (resc) {
                const float mnew = fmaxf(m_r, pmax);
                alpha = __expf(m_r - mnew);
                m_r = mnew;
                m2 = mnew * LOG2E;
            }
            float p[4][4];
            float psum = 0.f;
#pragma unroll
            for (int mt = 0; mt < 4; ++mt)
#pragma unroll
            for (int r = 0; r < 4; ++r) {
                const float pv = (cls[mt] == 0) ? 0.f
                                : exp2f(fmaf(sc[mt][r], LOG2E, -m2));
                p[mt][r] = pv;
                psum += pv;
            }
            psum += __shfl_xor(psum, 16, 64);
            psum += __shfl_xor(psum, 32, 64);
            l_r = l_r * alpha + psum;

            int pk01[4], pk23[4];
#pragma unroll
            for (int mt = 0; mt < 4; ++mt) {
                asm("v_cvt_pk_bf16_f32 %0, %1, %2" : "=v"(pk01[mt]) : "v"(p[mt][0]), "v"(p[mt][1]));
                asm("v_cvt_pk_bf16_f32 %0, %1, %2" : "=v"(pk23[mt]) : "v"(p[mt][2]), "v"(p[mt][3]));
            }
            const int srcA = ((g & 1) * 2) * 16 + n15;
            const int srcB = srcA + 16;
            const bool selHi = (g >> 1) != 0;
            if (resc) {
                float aO[4];
#pragma unroll
                for (int r = 0; r < 4; ++r) aO[r] = __shfl(alpha, 4 * g + r, 64);
#pragma unroll
                for (int dt = 0; dt < 4; ++dt)
#pragma unroll
                for (int r = 0; r < 4; ++r) oacc[dt][r] *= aO[r];
            }
#pragma unroll
            for (int kh = 0; kh < 2; ++kh) {
                if (cls[2 * kh] == 0 && cls[2 * kh + 1] == 0) continue;
                const int a0l = __shfl(pk01[2 * kh], srcA, 64);
                const int a0h = __shfl(pk01[2 * kh + 1], srcA, 64);
                const int a1l = __shfl(pk23[2 * kh], srcA, 64);
                const int a1h = __shfl(pk23[2 * kh + 1], srcA, 64);
                const int a2l = __shfl(pk01[2 * kh], srcB, 64);
                const int a2h = __shfl(pk01[2 * kh + 1], srcB, 64);
                const int a3l = __shfl(pk23[2 * kh], srcB, 64);
                const int a3h = __shfl(pk23[2 * kh + 1], srcB, 64);
                union { int i[4]; bf16x8 v; } au;
                au.i[0] = selHi ? a0h : a0l;
                au.i[1] = selHi ? a1h : a1l;
                au.i[2] = selHi ? a2h : a2l;
                au.i[3] = selHi ? a3h : a3l;
                __builtin_amdgcn_s_setprio(1);
#pragma unroll
                for (int dt = 0; dt < 4; ++dt) {
                    bf16x8 bv = *(const bf16x8*)(Vc + cb * 4096 + (kh * 4 + dt) * 512 + lane * 8);
                    oacc[dt] = __builtin_amdgcn_mfma_f32_16x16x32_bf16(au.v, bv, oacc[dt], 0, 0, 0);
                }
                __builtin_amdgcn_s_setprio(0);
            }
        }

        if (gs + 1 < g1) STORE_V(nb);
    }

    // ---- epilogue: write partial (m,l) and normalized partial O ----
    if (g == 0)
        *(float2*)(mlP + ((size_t)hb * T_SEQ + qn + n15) * 2) = make_float2(m_r, l_r);
#pragma unroll
    for (int r = 0; r < 4; ++r) {
        const float lq = __shfl(l_r, 4 * g + r, 64);
        const float linv = (lq > 0.f) ? 1.0f / lq : 0.f;
        short* dst = aoP + (rowbase + qn + 4 * g + r) * U_DIM + h * 64 + n15;
#pragma unroll
        for (int dt = 0; dt < 4; ++dt)
            dst[dt * 16] = (short)f2bf(oacc[dt][r] * linv);
    }
#undef STAGE_K
#undef LOAD_V
#undef STORE_V
}

// ---------------------------------------------------------------------------
// attn_combine: merge the two flash partials per row. Writes final ml and
// final (pre-relv) attention output into ao.
// ---------------------------------------------------------------------------
__global__ __launch_bounds__(256) void attn_combine(
        const float* __restrict__ ml1, const float* __restrict__ ml2,
        const short* __restrict__ ao2, short* __restrict__ ao,
        float* __restrict__ ml) {
    const int R = blockIdx.x * 64 + (threadIdx.x >> 2);
    const int hb = R >> 10, t = R & 1023;
    const int h = hb >> 3, b = hb & 7;
    const int d0 = (threadIdx.x & 3) * 16;
    const float2 p1 = *(const float2*)(ml1 + (size_t)R * 2);
    const float2 p2 = *(const float2*)(ml2 + (size_t)R * 2);
    const float m = fmaxf(p1.x, p2.x);
    const float w1 = p1.y * __expf(p1.x - m);
    const float w2 = (p2.y > 0.f) ? p2.y * __expf(p2.x - m) : 0.f;
    const float inv = 1.0f / (w1 + w2);
    const float a1 = w1 * inv, a2 = w2 * inv;
    const size_t off = (size_t)(b * T_SEQ + t) * U_DIM + h * 64 + d0;
    short* op = ao + off;
    const short* o2p = ao2 + off;
    bf16x8 x0 = *(const bf16x8*)op, x1 = *(const bf16x8*)(op + 8);
    bf16x8 y0 = *(const bf16x8*)o2p, y1 = *(const bf16x8*)(o2p + 8);
    const bool has2 = (w2 > 0.f);
    float o[16];
#pragma unroll
    for (int i = 0; i < 8; ++i) {
        float t0 = a1 * b2f(x0[i]);
        float t1 = a1 * b2f(x1[i]);
        o[i]     = has2 ? (t0 + a2 * b2f(y0[i])) : t0;
        o[8 + i] = has2 ? (t1 + a2 * b2f(y1[i])) : t1;
    }
    int4 o0, o1;
    o0.x = packbf(o[0], o[1]);   o0.y = packbf(o[2], o[3]);
    o0.z = packbf(o[4], o[5]);   o0.w = packbf(o[6], o[7]);
    o1.x = packbf(o[8], o[9]);   o1.y = packbf(o[10], o[11]);
    o1.z = packbf(o[12], o[13]); o1.w = packbf(o[14], o[15]);
    *(int4*)op = o0;
    *(int4*)(op + 8) = o1;
    if ((threadIdx.x & 3) == 0)
        *(float2*)(ml + (size_t)R * 2) = make_float2(m, w1 + w2);
}

// ---------------------------------------------------------------------------
// band_relv: recompute 17-wide diagonal band softmax weights from (m,l),
// add rel-v term (far mass = 1 - band mass goes to pe_v[0]) into ao (RMW).
// ---------------------------------------------------------------------------
__global__ __launch_bounds__(256) void band_relv(
        const short* __restrict__ qe, const short* __restrict__ ke,
        const float* __restrict__ pe_k, const float* __restrict__ pe_v,
        const float* __restrict__ ml, short* __restrict__ ao) {
    __shared__ float pek[17 * 64];
    __shared__ float pev[17 * 64];
    const int tb = blockIdx.x, hb = blockIdx.y;
    const int h = hb >> 3, b = hb & 7;
    const int tid = threadIdx.x;
    for (int i = tid; i < 17 * 64; i += 256) {
        pek[i] = b2f((short)f2bf(pe_k[i]));   // match main kernel's bf16 rounding
        pev[i] = pe_v[i];
    }
    __syncthreads();

    const int t = tb * 64 + (tid >> 2);
    const int p = (tid & 3) * 16;
    const short* qp = qe + (size_t)(b * T_SEQ + t) * U_DIM + h * 64 + p;
    bf16x8 qa = *(const bf16x8*)qp, qb2 = *(const bf16x8*)(qp + 8);
    float qv[16];
#pragma unroll
    for (int i = 0; i < 8; ++i) { qv[i] = b2f(qa[i]); qv[8 + i] = b2f(qb2[i]); }

    float dots[17];
#pragma unroll
    for (int ri = 0; ri < 17; ++ri) {
        const int s = t - 16 + ri;
        float acc = 0.f;
        if (s >= 0) {
            const short* kp = ke + (size_t)(b * T_SEQ + s) * U_DIM + h * 64 + p;
            bf16x8 ka = *(const bf16x8*)kp, kb2 = *(const bf16x8*)(kp + 8);
#pragma unroll
            for (int d = 0; d < 8; ++d) {
                acc += qv[d] * b2f(ka[d]);
                acc += qv[8 + d] * b2f(kb2[d]);
            }
#pragma unroll
            for (int d = 0; d < 16; ++d) acc += qv[d] * pek[ri * 64 + p + d];
        }
        dots[ri] = acc;
    }
#pragma unroll
    for (int ri = 0; ri < 17; ++ri) {
        dots[ri] += __shfl_xor(dots[ri], 1, 64);
        dots[ri] += __shfl_xor(dots[ri], 2, 64);
    }

    const float2 mlv = *(const float2*)(ml + ((size_t)hb * T_SEQ + t) * 2);
    const float m = mlv.x, linv = 1.0f / mlv.y;
    float wv[17];
    float wsum = 0.f;
#pragma unroll
    for (int ri = 0; ri < 17; ++ri) {
        const int s = t - 16 + ri;
        const float wr = (s >= 0) ? __expf(dots[ri] * 0.125f - m) * linv : 0.f;
        wv[ri] = wr;
        wsum += wr;
    }
    wv[0] += 1.0f - wsum;   // far-bucket mass (all s <= t-17)

    float relv[16];
#pragma unroll
    for (int d = 0; d < 16; ++d) relv[d] = 0.f;
#pragma unroll
    for (int ri = 0; ri < 17; ++ri)
#pragma unroll
        for (int d = 0; d < 16; ++d) relv[d] += wv[ri] * pev[ri * 64 + p + d];

    short* op = ao + (size_t)(b * T_SEQ + t) * U_DIM + h * 64 + p;
    bf16x8 a0 = *(const bf16x8*)op, a1 = *(const bf16x8*)(op + 8);
    int4 o0, o1;
    o0.x = packbf(b2f(a0[0]) + relv[0],  b2f(a0[1]) + relv[1]);
    o0.y = packbf(b2f(a0[2]) + relv[2],  b2f(a0[3]) + relv[3]);
    o0.z = packbf(b2f(a0[4]) + relv[4],  b2f(a0[5]) + relv[5]);
    o0.w = packbf(b2f(a0[6]) + relv[6],  b2f(a0[7]) + relv[7]);
    o1.x = packbf(b2f(a1[0]) + relv[8],  b2f(a1[1]) + relv[9]);
    o1.y = packbf(b2f(a1[2]) + relv[10], b2f(a1[3]) + relv[11]);
    o1.z = packbf(b2f(a1[4]) + relv[12], b2f(a1[5]) + relv[13]);
    o1.w = packbf(b2f(a1[6]) + relv[14], b2f(a1[7]) + relv[15]);
    *(int4*)op = o0;
    *(int4*)(op + 8) = o1;
}

// ---------------------------------------------------------------------------
// LayerNorm: one wave per row, shuffle-only reductions.
// ---------------------------------------------------------------------------
__global__ __launch_bounds__(256) void ln_kernel(float* __restrict__ io,
                                                 const float* __restrict__ gamma,
                                                 const float* __restrict__ beta) {
    const int row = blockIdx.x * 4 + (threadIdx.x >> 6);
    const int lane = threadIdx.x & 63;
    float* rp = io + (size_t)row * 512 + lane * 8;
    float4 a = *(const float4*)rp;
    float4 c = *(const float4*)(rp + 4);
    float v[8] = {a.x, a.y, a.z, a.w, c.x, c.y, c.z, c.w};

    float s = v[0] + v[1] + v[2] + v[3] + v[4] + v[5] + v[6] + v[7];
#pragma unroll
    for (int off = 1; off < 64; off <<= 1) s += __shfl_xor(s, off, 64);
    const float mu = s * (1.0f / 512.0f);

    float sq = 0.f;
#pragma unroll
    for (int i = 0; i < 8; ++i) { v[i] -= mu; sq += v[i] * v[i]; }
#pragma unroll
    for (int off = 1; off < 64; off <<= 1) sq += __shfl_xor(sq, off, 64);
    const float rs = rsqrtf(sq * (1.0f / 512.0f) + LN_EPS);

    const float4 g0 = *(const float4*)(gamma + lane * 8);
    const float4 g1 = *(const float4*)(gamma + lane * 8 + 4);
    const float4 b0 = *(const float4*)(beta + lane * 8);
    const float4 b1 = *(const float4*)(beta + lane * 8 + 4);
    float4 o0, o1;
    o0.x = v[0] * rs * g0.x + b0.x;
    o0.y = v[1] * rs * g0.y + b0.y;
    o0.z = v[2] * rs * g0.z + b0.z;
    o0.w = v[3] * rs * g0.w + b0.w;
    o1.x = v[4] * rs * g1.x + b1.x;
    o1.y = v[5] * rs * g1.y + b1.y;
    o1.z = v[6] * rs * g1.z + b1.z;
    o1.w = v[7] * rs * g1.w + b1.w;
    *(float4*)rp = o0;
    *(float4*)(rp + 4) = o1;
}

// ---------------------------------------------------------------------------
extern "C" void kernel_launch(void* const* d_in, const int* in_sizes, int n_in,
                              void* d_out, int out_size, void* d_ws, size_t ws_size,
                              hipStream_t stream) {
    const float* q     = (const float*)d_in[0];
    const float* k     = (const float*)d_in[1];
    const float* v     = (const float*)d_in[2];
    const float* Wq    = (const float*)d_in[3];
    const float* bq    = (const float*)d_in[4];
    const float* Wk    = (const float*)d_in[5];
    const float* bk    = (const float*)d_in[6];
    const float* Wv    = (const float*)d_in[7];
    const float* bv    = (const float*)d_in[8];
    const float* Wo    = (const float*)d_in[9];
    const float* bo    = (const float*)d_in[10];
    const float* gamma = (const float*)d_in[11];
    const float* beta  = (const float*)d_in[12];
    const float* pe_k  = (const float*)d_in[13];
    const float* pe_v  = (const float*)d_in[14];
    float* out = (float*)d_out;

    char* base = (char*)d_ws;
    short* qe = (short*)(base);                          // bf16 embeddings, 8 MB each
    short* ke = (short*)(base + (((size_t)8) << 20));
    short* ve = (short*)(base + (((size_t)16) << 20));
    short* ao = (short*)(base + (((size_t)24) << 20));
    short* wt = (short*)(base + (((size_t)32) << 20));   // 4 x 512 KB bf16 Wt
    float* ml = (float*)(base + (((size_t)34) << 20));   // [64][1024][2] fp32
    float* ml1 = (float*)(base + (((size_t)35) << 20));  // partial (m,l), half 0
    short* qb = (short*)(base + (((size_t)36) << 20));   // bf16 inputs, 8 MB each
    short* kb = (short*)(base + (((size_t)44) << 20));
    short* vb = (short*)(base + (((size_t)52) << 20));
    // after the QKV gemm, qb/kb are dead: reuse for attn partials
    short* ao2 = qb;                                      // partial O, half 1 (8 MB)
    float* ml2 = (float*)kb;                              // partial (m,l), half 1
    short* wtq = wt, *wtk = wt + 262144, *wtv = wt + 2 * 262144, *wto = wt + 3 * 262144;

    prep_all<<<dim3(2304), 256, 0, stream>>>(Wq, Wk, Wv, Wo, wt, q, k, v, qb, kb, vb);
    gemm_mfma<0, 128, 64><<<dim3(64, 8, 3), 256, 0, stream>>>(
        qb, kb, vb, wtq, wtk, wtv, bq, bk, bv, nullptr, qe, ke, ve);
    attn_mfma<<<dim3(2048), 256, 0, stream>>>(qe, ke, ve, pe_k, ml1, ml2, ao, ao2);
    attn_combine<<<dim3(1024), 256, 0, stream>>>(ml1, ml2, ao2, ao, ml);
    band_relv<<<dim3(16, 64), 256, 0, stream>>>(qe, ke, pe_k, pe_v, ml, ao);
    gemm_mfma<1, 64, 128><<<dim3(128, 4, 1), 256, 0, stream>>>(
        ao, ao, ao, wto, wto, wto, bo, bo, bo, q, out, out, out);
    ln_kernel<<<dim3(2048), 256, 0, stream>>>(out, gamma, beta);
}

// Round 6
// 239.699 us; speedup vs baseline: 1.0930x; 1.0930x over previous
//
#include <hip/hip_runtime.h>
#include <hip/hip_bf16.h>

#define T_SEQ 1024
#define U_DIM 512
#define LN_EPS 1e-3f
#define LOG2E 1.44269504f

typedef float  f32x4  __attribute__((ext_vector_type(4)));
typedef short  bf16x8 __attribute__((ext_vector_type(8)));

__device__ __forceinline__ unsigned short f2bf(float f) {
    union { float f; unsigned u; } x; x.f = f;
    unsigned r = x.u + 0x7fffu + ((x.u >> 16) & 1u);   // RNE
    return (unsigned short)(r >> 16);
}
__device__ __forceinline__ float b2f(short s) {
    union { unsigned u; float f; } x; x.u = ((unsigned)(unsigned short)s) << 16;
    return x.f;
}
__device__ __forceinline__ int packbf(float a, float b) {
    return (int)((unsigned)f2bf(a) | ((unsigned)f2bf(b) << 16));
}
__device__ __forceinline__ void async_copy16(void* lds, const void* g) {
    __builtin_amdgcn_global_load_lds((const __attribute__((address_space(1))) void*)g,
                                     (__attribute__((address_space(3))) void*)lds, 16, 0, 0);
}

#define WAITV(N) asm volatile("s_waitcnt vmcnt(" #N ")" ::: "memory")

// ---------------------------------------------------------------------------
// prep_wt: W[k][n] fp32 -> Wt[n][k] bf16, 4 matrices. 256 blocks.
// ---------------------------------------------------------------------------
__global__ __launch_bounds__(256) void prep_wt(
        const float* __restrict__ Wq, const float* __restrict__ Wk,
        const float* __restrict__ Wv, const float* __restrict__ Wo,
        short* __restrict__ wt) {
    __shared__ float Ws[64][65];
    const int bid = blockIdx.x, t = threadIdx.x;
    const int z = bid >> 6, tile = bid & 63;
    const float* W = (z == 0) ? Wq : (z == 1) ? Wk : (z == 2) ? Wv : Wo;
    short* Wt = wt + (size_t)z * 262144;
    const int k0 = (tile >> 3) * 64, n0 = (tile & 7) * 64;
    {
        const int kr = t >> 2, cs = (t & 3) * 16;
        const float4* src = (const float4*)(W + (size_t)(k0 + kr) * 512 + n0 + cs);
#pragma unroll
        for (int i = 0; i < 4; ++i) {
            float4 vv = src[i];
            Ws[kr][cs + 4 * i + 0] = vv.x;
            Ws[kr][cs + 4 * i + 1] = vv.y;
            Ws[kr][cs + 4 * i + 2] = vv.z;
            Ws[kr][cs + 4 * i + 3] = vv.w;
        }
    }
    __syncthreads();
    {
        const int nr = t >> 2, ks = (t & 3) * 16;
        int4 w0, w1;
        w0.x = packbf(Ws[ks + 0][nr], Ws[ks + 1][nr]);
        w0.y = packbf(Ws[ks + 2][nr], Ws[ks + 3][nr]);
        w0.z = packbf(Ws[ks + 4][nr], Ws[ks + 5][nr]);
        w0.w = packbf(Ws[ks + 6][nr], Ws[ks + 7][nr]);
        w1.x = packbf(Ws[ks + 8][nr], Ws[ks + 9][nr]);
        w1.y = packbf(Ws[ks + 10][nr], Ws[ks + 11][nr]);
        w1.z = packbf(Ws[ks + 12][nr], Ws[ks + 13][nr]);
        w1.w = packbf(Ws[ks + 14][nr], Ws[ks + 15][nr]);
        short* dst = Wt + (size_t)(n0 + nr) * 512 + k0 + ks;
        *(int4*)dst = w0;
        *(int4*)(dst + 8) = w1;
    }
}

// ---------------------------------------------------------------------------
// gemm_cvt: QKV projection. A fp32 [8192][512], convert-staged into LDS by
// all threads (coalesced 16-lanes/row loads); B bf16 Wt async-staged.
// BM=BN=128, BK=64, double-buffered, 1 barrier/iter. bf16 out. (round-1
// measured 63.5 us — best known for the fp32-input gemm.)
// ---------------------------------------------------------------------------
__global__ __launch_bounds__(256) void gemm_cvt(
        const float* __restrict__ A0, const float* __restrict__ A1, const float* __restrict__ A2,
        const short* __restrict__ Wt0, const short* __restrict__ Wt1, const short* __restrict__ Wt2,
        const float* __restrict__ b0p, const float* __restrict__ b1p, const float* __restrict__ b2p,
        short* __restrict__ O0, short* __restrict__ O1, short* __restrict__ O2) {
    __shared__ short As[2 * 8192];
    __shared__ short Bs[2 * 8192];

    const int z = blockIdx.z;
    const float* Av = (z == 0) ? A0 : (z == 1) ? A1 : A2;
    const short* Wz = (z == 0) ? Wt0 : (z == 1) ? Wt1 : Wt2;
    const float* bz = (z == 0) ? b0p : (z == 1) ? b1p : b2p;
    short* Ov = (z == 0) ? O0 : (z == 1) ? O1 : O2;

    const int tid = threadIdx.x;
    const int m0 = blockIdx.x * 128, n0 = blockIdx.y * 128;
    const int w = tid >> 6, lane = tid & 63;
    const int n15 = lane & 15, g = lane >> 4;
    const int mh = w >> 1, nh = w & 1;
    const int lr = tid >> 4, c4 = tid & 15;   // staging: 16 lanes per row

    f32x4 acc[4][4];
#pragma unroll
    for (int i = 0; i < 4; ++i)
#pragma unroll
        for (int j = 0; j < 4; ++j) acc[i][j] = (f32x4){0.f, 0.f, 0.f, 0.f};

    float4 areg[8];

// coalesced fp32 A load: instr i reads 4 dense 256B row-segments (rows lr+16i)
#define LOAD_A(CK)                                                                       \
    do {                                                                                 \
        const float* abase = Av + (size_t)(m0 + lr) * 512 + (CK) * 64 + c4 * 4;          \
        _Pragma("unroll")                                                                \
        for (int i = 0; i < 8; ++i) areg[i] = *(const float4*)(abase + (size_t)8192 * i); \
    } while (0)

// scatter to MFMA cell layout: element (row,k): cell=(k>>5)*8+(row>>4),
// slot=(row&15)+16*((k&31)>>3), short off=k&7. Thread holds k=c4*4..c4*4+3.
#define STORE_A(BUF)                                                                     \
    do {                                                                                 \
        short* sb = As + (BUF) * 8192 + (c4 >> 3) * 8 * 512 + lr * 8 +                   \
                    ((c4 & 7) >> 1) * 128 + (c4 & 1) * 4;                                \
        _Pragma("unroll")                                                                \
        for (int i = 0; i < 8; ++i) {                                                    \
            int2 wv;                                                                     \
            wv.x = packbf(areg[i].x, areg[i].y);                                         \
            wv.y = packbf(areg[i].z, areg[i].w);                                         \
            *(int2*)(sb + i * 512) = wv;                                                 \
        }                                                                                \
    } while (0)

#define STAGE_B(CK, BUF)                                                                 \
    do {                                                                                 \
        if (w < 2) {                                                                     \
            _Pragma("unroll")                                                            \
            for (int i = 0; i < 8; ++i) {                                                \
                const int kc = i >> 2, nt = w * 4 + (i & 3);                             \
                const short* gp = Wz + (size_t)(n0 + nt * 16 + n15) * 512 + (CK) * 64 + kc * 32 + g * 8; \
                async_copy16(Bs + (BUF) * 8192 + (kc * 8 + nt) * 512, gp);               \
            }                                                                            \
        }                                                                                \
    } while (0)

    // prologue
    LOAD_A(0);
    STORE_A(0);
    STAGE_B(0, 0);
    LOAD_A(1);

    for (int ck = 0; ck < 8; ++ck) {
        const int cb = ck & 1, nb = cb ^ 1;
        __syncthreads();
        if (ck < 7) STAGE_B(ck + 1, nb);
#pragma unroll
        for (int kc = 0; kc < 2; ++kc) {
            bf16x8 af[4], bfv[4];
#pragma unroll
            for (int i = 0; i < 4; ++i)
                af[i] = *(const bf16x8*)(As + cb * 8192 + (kc * 8 + mh * 4 + i) * 512 + lane * 8);
#pragma unroll
            for (int j = 0; j < 4; ++j)
                bfv[j] = *(const bf16x8*)(Bs + cb * 8192 + (kc * 8 + nh * 4 + j) * 512 + lane * 8);
#pragma unroll
            for (int i = 0; i < 4; ++i)
#pragma unroll
                for (int j = 0; j < 4; ++j)
                    acc[i][j] = __builtin_amdgcn_mfma_f32_16x16x32_bf16(af[i], bfv[j], acc[i][j], 0, 0, 0);
        }
        if (ck < 7) {
            STORE_A(nb);
            if (ck < 6) LOAD_A(ck + 2);
        }
    }
#undef LOAD_A
#undef STORE_A
#undef STAGE_B

    // Epilogue: relu(x + bias) -> bf16, paired-lane packed stores
    const int mbase = m0 + mh * 64 + g * 4;
    const int nbase = n0 + nh * 64 + n15;
    const bool even = (n15 & 1) == 0;
    float bj[4];
#pragma unroll
    for (int j = 0; j < 4; ++j) bj[j] = bz[nbase + j * 16];

#pragma unroll
    for (int i = 0; i < 4; ++i) {
        const int mrow = mbase + i * 16;
#pragma unroll
        for (int j = 0; j < 4; ++j) {
            const int ncol = nbase + j * 16;
            f32x4 a = acc[i][j];
            float v0 = fmaxf(a[0] + bj[j], 0.f);
            float v1 = fmaxf(a[1] + bj[j], 0.f);
            float v2 = fmaxf(a[2] + bj[j], 0.f);
            float v3 = fmaxf(a[3] + bj[j], 0.f);
            unsigned t01 = (unsigned)packbf(v0, v1);
            unsigned t23 = (unsigned)packbf(v2, v3);
            unsigned x01 = (unsigned)__shfl_xor((int)t01, 1, 64);
            unsigned x23 = (unsigned)__shfl_xor((int)t23, 1, 64);
            if (even) {
                unsigned d0 = (t01 & 0xffffu) | (x01 << 16);
                unsigned d1 = (t01 >> 16) | (x01 & 0xffff0000u);
                *(unsigned*)(Ov + (size_t)(mrow + 0) * 512 + ncol) = d0;
                *(unsigned*)(Ov + (size_t)(mrow + 1) * 512 + ncol) = d1;
            } else {
                unsigned d2 = (x23 & 0xffffu) | (t23 << 16);
                unsigned d3 = (x23 >> 16) | (t23 & 0xffff0000u);
                *(unsigned*)(Ov + (size_t)(mrow + 2) * 512 + ncol - 1) = d2;
                *(unsigned*)(Ov + (size_t)(mrow + 3) * 512 + ncol - 1) = d3;
            }
        }
    }
}

// ---------------------------------------------------------------------------
// gemm_pipe: out-projection. A bf16, counted-vmcnt 4-deep pipeline. BK=32,
// 4 LDS buffers, prefetch depth 3. fp32 out + residual after relu.
// ---------------------------------------------------------------------------
template <int BM, int BN>
__global__ __launch_bounds__(256) void gemm_pipe(
        const short* __restrict__ Ab, const short* __restrict__ Wz,
        const float* __restrict__ bz, const float* __restrict__ resid,
        float* __restrict__ Oz) {
    constexpr int ASZ = BM * 32;          // shorts per A tile
    constexpr int BSZ = BN * 32;          // shorts per B tile
    constexpr int TSZ = ASZ + BSZ;
    constexpr int NA  = BM / 16;          // A cells (16 rows x 32 k each)
    constexpr int NB  = BN / 16;          // B cells
    constexpr int MW  = BM / 64;          // waves along m
    constexpr int NW  = 4 / MW;           // waves along n
    constexpr int AJ  = BN / (16 * NW);   // n-frags per wave
    constexpr int LPW = (NA + NB) / 4;    // loads per wave per tile
    static_assert((NA + NB) % 4 == 0, "cells divisible by waves");
    __shared__ short Ls[4 * TSZ];

    const int tid = threadIdx.x;
    const int m0 = blockIdx.x * BM, n0 = blockIdx.y * BN;
    const int w = tid >> 6, lane = tid & 63;
    const int n15 = lane & 15, g = lane >> 4;
    const int mh = w / NW, nh = w % NW;

    f32x4 acc[4][AJ];
#pragma unroll
    for (int i = 0; i < 4; ++i)
#pragma unroll
        for (int j = 0; j < AJ; ++j) acc[i][j] = (f32x4){0.f, 0.f, 0.f, 0.f};

    const short* gsrc[LPW];
    int loff[LPW];
#pragma unroll
    for (int cl = 0; cl < LPW; ++cl) {
        const int cid = w * LPW + cl;
        if (cid < NA) {
            gsrc[cl] = Ab + (size_t)(m0 + cid * 16 + n15) * 512 + g * 8;
            loff[cl] = cid * 512;
        } else {
            const int c2 = cid - NA;
            gsrc[cl] = Wz + (size_t)(n0 + c2 * 16 + n15) * 512 + g * 8;
            loff[cl] = ASZ + c2 * 512;
        }
    }

#define STAGE(CK, BUF)                                                                   \
    do {                                                                                 \
        _Pragma("unroll")                                                                \
        for (int cl = 0; cl < LPW; ++cl)                                                 \
            async_copy16(Ls + (BUF) * TSZ + loff[cl], gsrc[cl] + (CK) * 32);             \
    } while (0)

    STAGE(0, 0);
    STAGE(1, 1);
    STAGE(2, 2);

    for (int ck = 0; ck < 16; ++ck) {
        if (ck < 14) {
            if constexpr (LPW == 3) WAITV(6); else WAITV(4);
        } else if (ck == 14) {
            if constexpr (LPW == 3) WAITV(3); else WAITV(2);
        } else {
            WAITV(0);
        }
        __builtin_amdgcn_s_barrier();
        __builtin_amdgcn_sched_barrier(0);
        if (ck + 3 <= 15) STAGE(ck + 3, (ck + 3) & 3);
        const int cb = ck & 3;
        bf16x8 af[4], bfv[AJ];
#pragma unroll
        for (int i = 0; i < 4; ++i)
            af[i] = *(const bf16x8*)(Ls + cb * TSZ + (mh * 4 + i) * 512 + lane * 8);
#pragma unroll
        for (int j = 0; j < AJ; ++j)
            bfv[j] = *(const bf16x8*)(Ls + cb * TSZ + ASZ + (nh * AJ + j) * 512 + lane * 8);
#pragma unroll
        for (int i = 0; i < 4; ++i)
#pragma unroll
            for (int j = 0; j < AJ; ++j)
                acc[i][j] = __builtin_amdgcn_mfma_f32_16x16x32_bf16(af[i], bfv[j], acc[i][j], 0, 0, 0);
    }
#undef STAGE

    const int mbase = m0 + mh * 64 + g * 4;
    const int nbase = n0 + nh * (AJ * 16) + n15;
    const bool even = (n15 & 1) == 0;
    float bj[AJ];
#pragma unroll
    for (int j = 0; j < AJ; ++j) bj[j] = bz[nbase + j * 16];

#pragma unroll
    for (int i = 0; i < 4; ++i) {
        const int mrow = mbase + i * 16;
#pragma unroll
        for (int j = 0; j < AJ; ++j) {
            const int ncol = nbase + j * 16;
            f32x4 a = acc[i][j];
            float v0 = fmaxf(a[0] + bj[j], 0.f);
            float v1 = fmaxf(a[1] + bj[j], 0.f);
            float v2 = fmaxf(a[2] + bj[j], 0.f);
            float v3 = fmaxf(a[3] + bj[j], 0.f);
            float x0 = __shfl_xor(v0, 1, 64);
            float x1 = __shfl_xor(v1, 1, 64);
            float x2 = __shfl_xor(v2, 1, 64);
            float x3 = __shfl_xor(v3, 1, 64);
            if (even) {
                float2 r0 = *(const float2*)(resid + (size_t)(mrow + 0) * 512 + ncol);
                float2 r1 = *(const float2*)(resid + (size_t)(mrow + 1) * 512 + ncol);
                *(float2*)(Oz + (size_t)(mrow + 0) * 512 + ncol) = make_float2(v0 + r0.x, x0 + r0.y);
                *(float2*)(Oz + (size_t)(mrow + 1) * 512 + ncol) = make_float2(v1 + r1.x, x1 + r1.y);
            } else {
                float2 r2 = *(const float2*)(resid + (size_t)(mrow + 2) * 512 + ncol - 1);
                float2 r3 = *(const float2*)(resid + (size_t)(mrow + 3) * 512 + ncol - 1);
                *(float2*)(Oz + (size_t)(mrow + 2) * 512 + ncol - 1) = make_float2(x2 + r2.x, v2 + r2.y);
                *(float2*)(Oz + (size_t)(mrow + 3) * 512 + ncol - 1) = make_float2(x3 + r3.x, v3 + r3.y);
            }
        }
    }
}

// ---------------------------------------------------------------------------
// MFMA flash attention, unpaired, CU-balanced ranks {r,r+4,15-r,11-r}.
// Q pre-scaled by 0.125 (exact exponent shift). Log2-domain softmax.
// P->bf16 via v_cvt_pk_bf16_f32. Defer-max (THR=8). setprio on MFMA clusters.
// (round-3/4 version, measured 53.4 us.)
// ---------------------------------------------------------------------------
__global__ __launch_bounds__(256) void attn_mfma(
        const short* __restrict__ qe, const short* __restrict__ ke,
        const short* __restrict__ ve, const float* __restrict__ pe_k,
        float* __restrict__ ml, short* __restrict__ ao) {
    __shared__ short Kc[2 * 4096];    // 8 cells x 512 shorts per buf: (kh*4+mt)
    __shared__ short Vc[2 * 4096];    // 8 cells: (kh*4+dt)
    __shared__ float qpeS[4 * 16 * 17];

    const int tid = threadIdx.x;
    const int bid = blockIdx.x;
    const int q4 = bid >> 8, r4 = bid & 3;
    const int rank = (q4 < 2) ? (r4 + 4 * q4) : (15 - (r4 + 4 * (q4 - 2)));
    const int hb = (bid >> 2) & 63;
    const int tt = 15 - rank;                      // this block's q-tile
    const int h = hb >> 3, b = hb & 7;
    const int w = tid >> 6, lane = tid & 63;
    const int g = lane >> 4, n15 = lane & 15;
    const int sp = tid & 31, dbase = (tid >> 5) * 8;
    float* qpeW = qpeS + w * (16 * 17);

    const size_t rowbase = (size_t)b * T_SEQ;

    const int qn = tt * 64 + w * 16;
    bf16x8 Bq[2];
    float qpe0 = 0.f;
    float m_r = -1.0e38f, l_r = 0.f, m2 = -1.4427e38f;
    f32x4 oacc[4];

    // ---- setup: load Q frags (scaled by 1/8 exactly), qpe table, state ----
    {
#pragma unroll
        for (int kh = 0; kh < 2; ++kh) {
            bf16x8 t = *(const bf16x8*)(qe + (rowbase + qn + n15) * U_DIM + h * 64 + kh * 32 + g * 8);
#pragma unroll
            for (int i2 = 0; i2 < 8; ++i2) {
                unsigned short u = (unsigned short)t[i2];
                t[i2] = (short)(((u & 0x7f80u) > 0x0180u) ? (unsigned short)(u - 0x0180u)
                                                          : (unsigned short)(u & 0x8000u));
            }
            Bq[kh] = t;
        }
        f32x4 qa[2];
        qa[0] = (f32x4){0.f, 0.f, 0.f, 0.f};
        qa[1] = (f32x4){0.f, 0.f, 0.f, 0.f};
#pragma unroll
        for (int mt = 0; mt < 2; ++mt)
#pragma unroll
        for (int kh = 0; kh < 2; ++kh) {
            const float* src = pe_k + (mt * 16 + n15) * 64 + kh * 32 + g * 8;
            float4 f0 = *(const float4*)src;
            float4 f1 = *(const float4*)(src + 4);
            bf16x8 fr;
            fr[0] = (short)f2bf(f0.x); fr[1] = (short)f2bf(f0.y);
            fr[2] = (short)f2bf(f0.z); fr[3] = (short)f2bf(f0.w);
            fr[4] = (short)f2bf(f1.x); fr[5] = (short)f2bf(f1.y);
            fr[6] = (short)f2bf(f1.z); fr[7] = (short)f2bf(f1.w);
            qa[mt] = __builtin_amdgcn_mfma_f32_16x16x32_bf16(fr, Bq[kh], qa[mt], 0, 0, 0);
        }
#pragma unroll
        for (int mt = 0; mt < 2; ++mt)
#pragma unroll
        for (int r = 0; r < 4; ++r) {
            const int ri = mt * 16 + 4 * g + r;
            if (ri <= 16) qpeW[n15 * 17 + ri] = qa[mt][r];
        }
        qpe0 = qpeW[n15 * 17];
#pragma unroll
        for (int dt = 0; dt < 4; ++dt) oacc[dt] = (f32x4){0.f, 0.f, 0.f, 0.f};
    }

#define STAGE_K(S, BUF)                                                                  \
    do {                                                                                 \
        _Pragma("unroll")                                                                \
        for (int j = 0; j < 2; ++j) {                                                    \
            const int cc = w * 2 + j, kh = cc >> 2, mt = cc & 3;                         \
            const short* gp = ke + (rowbase + (S) + mt * 16 + n15) * U_DIM + h * 64 + kh * 32 + g * 8; \
            async_copy16(Kc + (BUF) * 4096 + cc * 512, gp);                              \
        }                                                                                \
    } while (0)

#define LOAD_V(S)                                                                        \
    do {                                                                                 \
        const short* r0 = ve + (rowbase + (S) + 2 * sp) * U_DIM + h * 64 + dbase;        \
        vx = *(const bf16x8*)r0;                                                         \
        vy = *(const bf16x8*)(r0 + U_DIM);                                               \
    } while (0)

#define STORE_V(BUF)                                                                     \
    do {                                                                                 \
        const int vkh = sp >> 4, vg = (sp & 15) >> 2, vj = (sp & 3) * 2;                 \
        _Pragma("unroll")                                                                \
        for (int i = 0; i < 8; ++i) {                                                    \
            const int d = dbase + i;                                                     \
            int pv = (int)((unsigned short)vx[i]) | (((int)(unsigned short)vy[i]) << 16);\
            *(int*)(Vc + (BUF) * 4096 + (vkh * 4 + (d >> 4)) * 512 + ((d & 15) + 16 * vg) * 8 + vj) = pv; \
        }                                                                                \
    } while (0)

    bf16x8 vx, vy;
    STAGE_K(0, 0);
    LOAD_V(0);
    STORE_V(0);

    for (int gs = 0; gs <= tt; ++gs) {
        const int cb = gs & 1, nb = cb ^ 1;
        const int s0 = gs * 64;
        __syncthreads();
        if (gs < tt) {
            STAGE_K((gs + 1) * 64, nb);
            LOAD_V((gs + 1) * 64);
        }

        // ---- compute step at s0 ----
        {
            int cls[4];
#pragma unroll
            for (int mt = 0; mt < 4; ++mt) {
                const int slo = s0 + mt * 16;
                cls[mt] = (slo > qn + 15) ? 0 : ((slo + 31 < qn) ? 1 : 2);
            }
            f32x4 c[4];
#pragma unroll
            for (int mt = 0; mt < 4; ++mt) c[mt] = (f32x4){0.f, 0.f, 0.f, 0.f};
            __builtin_amdgcn_s_setprio(1);
#pragma unroll
            for (int mt = 0; mt < 4; ++mt) {
                if (!cls[mt]) continue;
#pragma unroll
                for (int kh = 0; kh < 2; ++kh) {
                    bf16x8 ak = *(const bf16x8*)(Kc + cb * 4096 + (kh * 4 + mt) * 512 + lane * 8);
                    c[mt] = __builtin_amdgcn_mfma_f32_16x16x32_bf16(ak, Bq[kh], c[mt], 0, 0, 0);
                }
            }
            __builtin_amdgcn_s_setprio(0);

            const int qg = qn + n15;
            float sc[4][4];
            float pmax = -3.0e38f;
#pragma unroll
            for (int mt = 0; mt < 4; ++mt) {
                if (cls[mt] == 0) {
#pragma unroll
                    for (int r = 0; r < 4; ++r) sc[mt][r] = -3.0e38f;
                } else if (cls[mt] == 1) {
#pragma unroll
                    for (int r = 0; r < 4; ++r) {
                        sc[mt][r] = c[mt][r] + qpe0;
                        pmax = fmaxf(pmax, sc[mt][r]);
                    }
                } else {
#pragma unroll
                    for (int r = 0; r < 4; ++r) {
                        const int sg = s0 + mt * 16 + 4 * g + r;
                        const int dlt = sg - qg;
                        if (dlt <= 0) {
                            const int ri = (dlt < -16) ? 0 : (dlt + 16);
                            sc[mt][r] = c[mt][r] + qpeW[n15 * 17 + ri];
                            pmax = fmaxf(pmax, sc[mt][r]);
                        } else {
                            sc[mt][r] = -3.0e38f;
                        }
                    }
                }
            }
            pmax = fmaxf(pmax, __shfl_xor(pmax, 16, 64));
            pmax = fmaxf(pmax, __shfl_xor(pmax, 32, 64));

            // defer-max: only rescale when some row's max grew past THR=8
            const bool resc = __any(pmax > m_r + 8.0f);
            float alpha = 1.0f;
            if (resc) {
                const float mnew = fmaxf(m_r, pmax);
                alpha = __expf(m_r - mnew);
                m_r = mnew;
                m2 = mnew * LOG2E;
            }
            float p[4][4];
            float psum = 0.f;
#pragma unroll
            for (int mt = 0; mt < 4; ++mt)
#pragma unroll
            for (int r = 0; r < 4; ++r) {
                const float pv = (cls[mt] == 0) ? 0.f
                                : exp2f(fmaf(sc[mt][r], LOG2E, -m2));
                p[mt][r] = pv;
                psum += pv;
            }
            psum += __shfl_xor(psum, 16, 64);
            psum += __shfl_xor(psum, 32, 64);
            l_r = l_r * alpha + psum;

            int pk01[4], pk23[4];
#pragma unroll
            for (int mt = 0; mt < 4; ++mt) {
                asm("v_cvt_pk_bf16_f32 %0, %1, %2" : "=v"(pk01[mt]) : "v"(p[mt][0]), "v"(p[mt][1]));
                asm("v_cvt_pk_bf16_f32 %0, %1, %2" : "=v"(pk23[mt]) : "v"(p[mt][2]), "v"(p[mt][3]));
            }
            const int srcA = ((g & 1) * 2) * 16 + n15;
            const int srcB = srcA + 16;
            const bool selHi = (g >> 1) != 0;
            if (resc) {
                float aO[4];
#pragma unroll
                for (int r = 0; r < 4; ++r) aO[r] = __shfl(alpha, 4 * g + r, 64);
#pragma unroll
                for (int dt = 0; dt < 4; ++dt)
#pragma unroll
                for (int r = 0; r < 4; ++r) oacc[dt][r] *= aO[r];
            }
#pragma unroll
            for (int kh = 0; kh < 2; ++kh) {
                if (cls[2 * kh] == 0 && cls[2 * kh + 1] == 0) continue;
                const int a0l = __shfl(pk01[2 * kh], srcA, 64);
                const int a0h = __shfl(pk01[2 * kh + 1], srcA, 64);
                const int a1l = __shfl(pk23[2 * kh], srcA, 64);
                const int a1h = __shfl(pk23[2 * kh + 1], srcA, 64);
                const int a2l = __shfl(pk01[2 * kh], srcB, 64);
                const int a2h = __shfl(pk01[2 * kh + 1], srcB, 64);
                const int a3l = __shfl(pk23[2 * kh], srcB, 64);
                const int a3h = __shfl(pk23[2 * kh + 1], srcB, 64);
                union { int i[4]; bf16x8 v; } au;
                au.i[0] = selHi ? a0h : a0l;
                au.i[1] = selHi ? a1h : a1l;
                au.i[2] = selHi ? a2h : a2l;
                au.i[3] = selHi ? a3h : a3l;
                __builtin_amdgcn_s_setprio(1);
#pragma unroll
                for (int dt = 0; dt < 4; ++dt) {
                    bf16x8 bv = *(const bf16x8*)(Vc + cb * 4096 + (kh * 4 + dt) * 512 + lane * 8);
                    oacc[dt] = __builtin_amdgcn_mfma_f32_16x16x32_bf16(au.v, bv, oacc[dt], 0, 0, 0);
                }
                __builtin_amdgcn_s_setprio(0);
            }
        }

        if (gs < tt) STORE_V(nb);
    }

    // ---- epilogue: write (m,l) and normalized O ----
    if (g == 0)
        *(float2*)(ml + ((size_t)hb * T_SEQ + qn + n15) * 2) = make_float2(m_r, l_r);
#pragma unroll
    for (int r = 0; r < 4; ++r) {
        const float lq = __shfl(l_r, 4 * g + r, 64);
        const float linv = 1.0f / lq;
        short* dst = ao + (rowbase + qn + 4 * g + r) * U_DIM + h * 64 + n15;
#pragma unroll
        for (int dt = 0; dt < 4; ++dt)
            dst[dt * 16] = (short)f2bf(oacc[dt][r] * linv);
    }
#undef STAGE_K
#undef LOAD_V
#undef STORE_V
}

// ---------------------------------------------------------------------------
// band_relv: recompute 17-wide diagonal band softmax weights from (m,l),
// add rel-v term (far mass = 1 - band mass goes to pe_v[0]) into ao (RMW).
// ---------------------------------------------------------------------------
__global__ __launch_bounds__(256) void band_relv(
        const short* __restrict__ qe, const short* __restrict__ ke,
        const float* __restrict__ pe_k, const float* __restrict__ pe_v,
        const float* __restrict__ ml, short* __restrict__ ao) {
    __shared__ float pek[17 * 64];
    __shared__ float pev[17 * 64];
    const int tb = blockIdx.x, hb = blockIdx.y;
    const int h = hb >> 3, b = hb & 7;
    const int tid = threadIdx.x;
    for (int i = tid; i < 17 * 64; i += 256) {
        pek[i] = b2f((short)f2bf(pe_k[i]));   // match main kernel's bf16 rounding
        pev[i] = pe_v[i];
    }
    __syncthreads();

    const int t = tb * 64 + (tid >> 2);
    const int p = (tid & 3) * 16;
    const short* qp = qe + (size_t)(b * T_SEQ + t) * U_DIM + h * 64 + p;
    bf16x8 qa = *(const bf16x8*)qp, qb2 = *(const bf16x8*)(qp + 8);
    float qv[16];
#pragma unroll
    for (int i = 0; i < 8; ++i) { qv[i] = b2f(qa[i]); qv[8 + i] = b2f(qb2[i]); }

    float dots[17];
#pragma unroll
    for (int ri = 0; ri < 17; ++ri) {
        const int s = t - 16 + ri;
        float acc = 0.f;
        if (s >= 0) {
            const short* kp = ke + (size_t)(b * T_SEQ + s) * U_DIM + h * 64 + p;
            bf16x8 ka = *(const bf16x8*)kp, kb2 = *(const bf16x8*)(kp + 8);
#pragma unroll
            for (int d = 0; d < 8; ++d) {
                acc += qv[d] * b2f(ka[d]);
                acc += qv[8 + d] * b2f(kb2[d]);
            }
#pragma unroll
            for (int d = 0; d < 16; ++d) acc += qv[d] * pek[ri * 64 + p + d];
        }
        dots[ri] = acc;
    }
#pragma unroll
    for (int ri = 0; ri < 17; ++ri) {
        dots[ri] += __shfl_xor(dots[ri], 1, 64);
        dots[ri] += __shfl_xor(dots[ri], 2, 64);
    }

    const float2 mlv = *(const float2*)(ml + ((size_t)hb * T_SEQ + t) * 2);
    const float m = mlv.x, linv = 1.0f / mlv.y;
    float wv[17];
    float wsum = 0.f;
#pragma unroll
    for (int ri = 0; ri < 17; ++ri) {
        const int s = t - 16 + ri;
        const float wr = (s >= 0) ? __expf(dots[ri] * 0.125f - m) * linv : 0.f;
        wv[ri] = wr;
        wsum += wr;
    }
    wv[0] += 1.0f - wsum;   // far-bucket mass (all s <= t-17)

    float relv[16];
#pragma unroll
    for (int d = 0; d < 16; ++d) relv[d] = 0.f;
#pragma unroll
    for (int ri = 0; ri < 17; ++ri)
#pragma unroll
        for (int d = 0; d < 16; ++d) relv[d] += wv[ri] * pev[ri * 64 + p + d];

    short* op = ao + (size_t)(b * T_SEQ + t) * U_DIM + h * 64 + p;
    bf16x8 a0 = *(const bf16x8*)op, a1 = *(const bf16x8*)(op + 8);
    int4 o0, o1;
    o0.x = packbf(b2f(a0[0]) + relv[0],  b2f(a0[1]) + relv[1]);
    o0.y = packbf(b2f(a0[2]) + relv[2],  b2f(a0[3]) + relv[3]);
    o0.z = packbf(b2f(a0[4]) + relv[4],  b2f(a0[5]) + relv[5]);
    o0.w = packbf(b2f(a0[6]) + relv[6],  b2f(a0[7]) + relv[7]);
    o1.x = packbf(b2f(a1[0]) + relv[8],  b2f(a1[1]) + relv[9]);
    o1.y = packbf(b2f(a1[2]) + relv[10], b2f(a1[3]) + relv[11]);
    o1.z = packbf(b2f(a1[4]) + relv[12], b2f(a1[5]) + relv[13]);
    o1.w = packbf(b2f(a1[6]) + relv[14], b2f(a1[7]) + relv[15]);
    *(int4*)op = o0;
    *(int4*)(op + 8) = o1;
}

// ---------------------------------------------------------------------------
// LayerNorm: one wave per row, shuffle-only reductions.
// ---------------------------------------------------------------------------
__global__ __launch_bounds__(256) void ln_kernel(float* __restrict__ io,
                                                 const float* __restrict__ gamma,
                                                 const float* __restrict__ beta) {
    const int row = blockIdx.x * 4 + (threadIdx.x >> 6);
    const int lane = threadIdx.x & 63;
    float* rp = io + (size_t)row * 512 + lane * 8;
    float4 a = *(const float4*)rp;
    float4 c = *(const float4*)(rp + 4);
    float v[8] = {a.x, a.y, a.z, a.w, c.x, c.y, c.z, c.w};

    float s = v[0] + v[1] + v[2] + v[3] + v[4] + v[5] + v[6] + v[7];
#pragma unroll
    for (int off = 1; off < 64; off <<= 1) s += __shfl_xor(s, off, 64);
    const float mu = s * (1.0f / 512.0f);

    float sq = 0.f;
#pragma unroll
    for (int i = 0; i < 8; ++i) { v[i] -= mu; sq += v[i] * v[i]; }
#pragma unroll
    for (int off = 1; off < 64; off <<= 1) sq += __shfl_xor(sq, off, 64);
    const float rs = rsqrtf(sq * (1.0f / 512.0f) + LN_EPS);

    const float4 g0 = *(const float4*)(gamma + lane * 8);
    const float4 g1 = *(const float4*)(gamma + lane * 8 + 4);
    const float4 b0 = *(const float4*)(beta + lane * 8);
    const float4 b1 = *(const float4*)(beta + lane * 8 + 4);
    float4 o0, o1;
    o0.x = v[0] * rs * g0.x + b0.x;
    o0.y = v[1] * rs * g0.y + b0.y;
    o0.z = v[2] * rs * g0.z + b0.z;
    o0.w = v[3] * rs * g0.w + b0.w;
    o1.x = v[4] * rs * g1.x + b1.x;
    o1.y = v[5] * rs * g1.y + b1.y;
    o1.z = v[6] * rs * g1.z + b1.z;
    o1.w = v[7] * rs * g1.w + b1.w;
    *(float4*)rp = o0;
    *(float4*)(rp + 4) = o1;
}

// ---------------------------------------------------------------------------
extern "C" void kernel_launch(void* const* d_in, const int* in_sizes, int n_in,
                              void* d_out, int out_size, void* d_ws, size_t ws_size,
                              hipStream_t stream) {
    const float* q     = (const float*)d_in[0];
    const float* k     = (const float*)d_in[1];
    const float* v     = (const float*)d_in[2];
    const float* Wq    = (const float*)d_in[3];
    const float* bq    = (const float*)d_in[4];
    const float* Wk    = (const float*)d_in[5];
    const float* bk    = (const float*)d_in[6];
    const float* Wv    = (const float*)d_in[7];
    const float* bv    = (const float*)d_in[8];
    const float* Wo    = (const float*)d_in[9];
    const float* bo    = (const float*)d_in[10];
    const float* gamma = (const float*)d_in[11];
    const float* beta  = (const float*)d_in[12];
    const float* pe_k  = (const float*)d_in[13];
    const float* pe_v  = (const float*)d_in[14];
    float* out = (float*)d_out;

    char* base = (char*)d_ws;
    short* qe = (short*)(base);                          // bf16 embeddings, 8 MB each
    short* ke = (short*)(base + (((size_t)8) << 20));
    short* ve = (short*)(base + (((size_t)16) << 20));
    short* ao = (short*)(base + (((size_t)24) << 20));
    short* wt = (short*)(base + (((size_t)32) << 20));   // 4 x 512 KB bf16 Wt
    float* ml = (float*)(base + (((size_t)34) << 20));   // [64][1024][2] fp32
    short* wtq = wt, *wtk = wt + 262144, *wtv = wt + 2 * 262144, *wto = wt + 3 * 262144;

    prep_wt<<<dim3(256), 256, 0, stream>>>(Wq, Wk, Wv, Wo, wt);
    gemm_cvt<<<dim3(64, 4, 3), 256, 0, stream>>>(
        q, k, v, wtq, wtk, wtv, bq, bk, bv, qe, ke, ve);
    attn_mfma<<<dim3(1024), 256, 0, stream>>>(qe, ke, ve, pe_k, ml, ao);
    band_relv<<<dim3(16, 64), 256, 0, stream>>>(qe, ke, pe_k, pe_v, ml, ao);
    gemm_pipe<64, 128><<<dim3(128, 4), 256, 0, stream>>>(ao, wto, bo, q, out);
    ln_kernel<<<dim3(2048), 256, 0, stream>>>(out, gamma, beta);
}